// Round 2
// baseline (364.796 us; speedup 1.0000x reference)
//
#include <hip/hip_runtime.h>
#include <stdint.h>

// Problem constants (B, LQ, LK, D fixed by the reference)
#define NB    32
#define SLQ   2048
#define SLK   2048
#define DD    128
#define QTILE 128          // q rows per workgroup (4 waves x 32)
#define KVB   64           // keys per block iteration
#define NKB   (SLK / KVB)  // 32

typedef __attribute__((ext_vector_type(8)))  short    bf16x8;
typedef __attribute__((ext_vector_type(16))) float    f32x16;
typedef __attribute__((ext_vector_type(4)))  float    f32x4v;
typedef __attribute__((ext_vector_type(4)))  uint32_t u32x4;
typedef __attribute__((ext_vector_type(2)))  uint32_t u32x2;

union FragU { uint32_t u[4]; bf16x8 v; };

__device__ __forceinline__ uint32_t rne_bf16(float f) {
    uint32_t u = __builtin_bit_cast(uint32_t, f);
    u += 0x7fffu + ((u >> 16) & 1u);   // round-to-nearest-even (finite values only here)
    return u >> 16;
}
__device__ __forceinline__ float bf16f(uint32_t bits) {
    return __builtin_bit_cast(float, bits << 16);
}

__global__ __launch_bounds__(256, 2)
void attn_fwd(const float* __restrict__ qp, const float* __restrict__ kp,
              const float* __restrict__ vp, const void* __restrict__ mp,
              float* __restrict__ op)
{
    // LDS: K tile (bf16, row-swizzled), V^T tile (bf16, row-swizzled), mask tile (bytes)
    __shared__ short   k_lds[KVB * DD];     // [64 key][128 d], rows 256B
    __shared__ short   vt_lds[DD * KVB];    // [128 d][64 key], rows 128B
    __shared__ uint8_t m_lds[QTILE * 80];   // [128 q][64 k + pad]
    __shared__ int     det_flags;

    const int tid  = threadIdx.x;
    const int lane = tid & 63;
    const int wv   = tid >> 6;   // wave 0..3
    const int l31  = lane & 31;
    const int hi2  = lane >> 5;  // 0/1

    // XCD-chunked swizzle: 512 WGs, 8 XCDs -> each XCD gets 64 consecutive work ids
    const int bid = blockIdx.x;
    const int wg  = (bid & 7) * 64 + (bid >> 3);
    const int b   = wg >> 4;            // batch
    const int q0  = (wg & 15) * QTILE;  // q tile origin

    // ---- mask dtype self-detection from first 4 KB (deterministic per input) ----
    // int32 bool array: bytes at offset%4!=0 are all zero. offset%8==4 bytes
    // distinguish int32 (some nonzero) from int64 (all zero).
    if (tid == 0) det_flags = 0;
    __syncthreads();
    {
        const u32x4 w = *(const u32x4*)((const char*)mp + tid * 16);
        const uint32_t any_hi    = (w.x | w.y | w.z | w.w) & 0xFFFFFF00u; // bytes %4 != 0
        const uint32_t any_mod84 = (w.y | w.w) & 0xFFu;                   // bytes %8 == 4
        const int f = (any_hi ? 1 : 0) | (any_mod84 ? 2 : 0);
        if (f) atomicOr(&det_flags, f);
    }
    __syncthreads();
    const int mflags = det_flags;
    const int mmode  = (mflags & 1) ? 0 : ((mflags & 2) ? 1 : 2);  // 0=u8, 1=i32, 2=i64

    const float scale = 0.08838834764831845f;  // 1/sqrt(128), folded into Q

    // ---- persistent Q fragments: B-operand of swapped QK^T ----
    // B[k=d][col=q]: lane holds Q[q=l31][d = 16*ks + 8*hi2 + j], j=0..7
    bf16x8 qf[8];
    {
        const float* qrow = qp + ((size_t)b * SLQ + (size_t)(q0 + wv * 32 + l31)) * DD;
        #pragma unroll
        for (int ks = 0; ks < 8; ++ks) {
            f32x4v x0 = *(const f32x4v*)(qrow + 16 * ks + 8 * hi2);
            f32x4v x1 = *(const f32x4v*)(qrow + 16 * ks + 8 * hi2 + 4);
            FragU f;
            f.u[0] = rne_bf16(x0.x * scale) | (rne_bf16(x0.y * scale) << 16);
            f.u[1] = rne_bf16(x0.z * scale) | (rne_bf16(x0.w * scale) << 16);
            f.u[2] = rne_bf16(x1.x * scale) | (rne_bf16(x1.y * scale) << 16);
            f.u[3] = rne_bf16(x1.z * scale) | (rne_bf16(x1.w * scale) << 16);
            qf[ks] = f.v;
        }
    }

    f32x16 oacc[4];
    #pragma unroll
    for (int i = 0; i < 4; ++i) {
        #pragma unroll
        for (int j = 0; j < 16; ++j) oacc[i][j] = 0.0f;
    }
    float psum = 0.0f;  // running sum of masked exp for q = l31 (this lane's keys)

    const float* kb0 = kp + (size_t)b * SLK * DD;
    const float* vb0 = vp + (size_t)b * SLK * DD;
    const size_t mrow0 = ((size_t)b * SLQ + q0) * SLK;  // element index of mask tile origin

    for (int kb = 0; kb < NKB; ++kb) {
        const int k0 = kb * KVB;
        const float* kbase = kb0 + (size_t)k0 * DD;
        const float* vbase = vb0 + (size_t)k0 * DD;

        // --- stage K: 64x128 f32 -> bf16 LDS, byte ^= ((row&7)<<4) swizzle (G4) ---
        #pragma unroll
        for (int j = 0; j < 8; ++j) {
            const int flat = (j * 256 + tid) * 4;  // element index in 64x128
            const int kk = flat >> 7;
            const int dd = flat & 127;
            f32x4v x = *(const f32x4v*)(kbase + flat);
            u32x2 w2;
            w2.x = rne_bf16(x.x) | (rne_bf16(x.y) << 16);
            w2.y = rne_bf16(x.z) | (rne_bf16(x.w) << 16);
            *(u32x2*)((char*)k_lds + kk * 256 + ((dd * 2) ^ ((kk & 7) << 4))) = w2;
        }
        // --- stage V transposed: coalesced column loads, bf16 pack, swizzled rows ---
        {
            const int d  = tid & 127;
            const int kh = tid >> 7;  // 0/1 -> key halves
            const float* vcol = vbase + (size_t)(32 * kh) * DD + d;
            char* vrow = (char*)vt_lds + d * 128;
            const int sw = (d & 7) << 4;
            #pragma unroll
            for (int jj = 0; jj < 8; ++jj) {
                float a0 = vcol[(4 * jj + 0) * DD];
                float a1 = vcol[(4 * jj + 1) * DD];
                float a2 = vcol[(4 * jj + 2) * DD];
                float a3 = vcol[(4 * jj + 3) * DD];
                u32x2 w2;
                w2.x = rne_bf16(a0) | (rne_bf16(a1) << 16);
                w2.y = rne_bf16(a2) | (rne_bf16(a3) << 16);
                const int keyb = (32 * kh + 4 * jj) * 2;
                *(u32x2*)(vrow + (keyb ^ sw)) = w2;
            }
        }
        // --- stage mask tile [128 q][64 k] -> 1 byte/elem, dtype-dispatched ---
        {
            const int qq   = tid >> 1;
            const int koff = (tid & 1) * 32;
            const size_t e0 = mrow0 + (size_t)qq * SLK + k0 + koff;  // element index
            if (mmode == 0) {
                // uint8 / bool bytes
                const uint8_t* src = (const uint8_t*)mp + e0;
                u32x4 a = *(const u32x4*)(src);
                u32x4 c = *(const u32x4*)(src + 16);
                *(u32x4*)(&m_lds[qq * 80 + koff])      = a;
                *(u32x4*)(&m_lds[qq * 80 + koff + 16]) = c;
            } else if (mmode == 1) {
                // int32 0/1 -> pack to bytes
                const uint32_t* src = (const uint32_t*)mp + e0;
                uint32_t packed[8];
                #pragma unroll
                for (int g = 0; g < 8; ++g) {
                    u32x4 a = *(const u32x4*)(src + 4 * g);
                    packed[g] = (a.x ? 1u : 0u) | (a.y ? 0x100u : 0u) |
                                (a.z ? 0x10000u : 0u) | (a.w ? 0x1000000u : 0u);
                }
                u32x4 o1; o1.x = packed[0]; o1.y = packed[1]; o1.z = packed[2]; o1.w = packed[3];
                u32x4 o2; o2.x = packed[4]; o2.y = packed[5]; o2.z = packed[6]; o2.w = packed[7];
                *(u32x4*)(&m_lds[qq * 80 + koff])      = o1;
                *(u32x4*)(&m_lds[qq * 80 + koff + 16]) = o2;
            } else {
                // int64 0/1 -> scalar fallback
                const uint64_t* src = (const uint64_t*)mp + e0;
                #pragma unroll
                for (int j = 0; j < 32; ++j) {
                    m_lds[qq * 80 + koff + j] = (src[j] != 0) ? 1u : 0u;
                }
            }
        }
        __syncthreads();

        // --- swapped QK^T: sacc[t] = S^T tile (keys 32t..32t+31 x 32 q) ---
        // A = K: row=key=l31(+32t), k = 16*ks + 8*hi2 + j ; B = Q frags
        f32x16 sacc[2];
        #pragma unroll
        for (int t = 0; t < 2; ++t) {
            #pragma unroll
            for (int j = 0; j < 16; ++j) sacc[t][j] = 0.0f;
        }
        #pragma unroll
        for (int t = 0; t < 2; ++t) {
            const int row = 32 * t + l31;
            const char* krow = (char*)k_lds + row * 256;
            const int sw = (row & 7) << 4;
            #pragma unroll
            for (int ks = 0; ks < 8; ++ks) {
                bf16x8 af = *(const bf16x8*)(krow + ((32 * ks + 16 * hi2) ^ sw));
                sacc[t] = __builtin_amdgcn_mfma_f32_32x32x16_bf16(af, qf[ks], sacc[t], 0, 0, 0);
            }
        }

        // --- exp (unstable, like reference), mask, row-sum, pack bf16 pairs ---
        // acc layout: col=q=l31, row(key rel) = (r&3) + 8*(r>>2) + 4*hi2 (+32t)
        const uint8_t* mrow = &m_lds[(32 * wv + l31) * 80];
        uint32_t pw[2][8];
        #pragma unroll
        for (int t = 0; t < 2; ++t) {
            #pragma unroll
            for (int rr = 0; rr < 4; ++rr) {
                const uint32_t mw = *(const uint32_t*)(mrow + 32 * t + 8 * rr + 4 * hi2);
                uint32_t bb[4];
                #pragma unroll
                for (int c = 0; c < 4; ++c) {
                    const float e = __expf(sacc[t][4 * rr + c]);
                    bb[c] = ((mw >> (8 * c)) & 0xffu) ? 0u : rne_bf16(e);
                    psum += bf16f(bb[c]);  // sum exactly what PV consumes
                }
                pw[t][2 * rr]     = bb[0] | (bb[1] << 16);
                pw[t][2 * rr + 1] = bb[2] | (bb[3] << 16);
            }
        }

        // --- PV: O[32q x 128d] += P[32x64] * V[64x128] ---
        // A-frag needs P[q=l31][key = 16*(2t+kss) + 8*hi2 + j]; half comes from lane^32
        #pragma unroll
        for (int t = 0; t < 2; ++t) {
            #pragma unroll
            for (int kss = 0; kss < 2; ++kss) {
                const uint32_t m0 = pw[t][4 * kss + 0];
                const uint32_t m1 = pw[t][4 * kss + 1];
                const uint32_t m2 = pw[t][4 * kss + 2];
                const uint32_t m3 = pw[t][4 * kss + 3];
                const uint32_t o0 = (uint32_t)__shfl_xor((int)m0, 32);
                const uint32_t o1 = (uint32_t)__shfl_xor((int)m1, 32);
                const uint32_t o2 = (uint32_t)__shfl_xor((int)m2, 32);
                const uint32_t o3 = (uint32_t)__shfl_xor((int)m3, 32);
                FragU af;
                af.u[0] = hi2 ? o2 : m0;
                af.u[1] = hi2 ? o3 : m1;
                af.u[2] = hi2 ? m2 : o0;
                af.u[3] = hi2 ? m3 : o1;
                const int keyb = 64 * t + 32 * kss + 16 * hi2;
                #pragma unroll
                for (int dt = 0; dt < 4; ++dt) {
                    const int drow = 32 * dt + l31;
                    bf16x8 vf = *(const bf16x8*)((char*)vt_lds + drow * 128 +
                                                 (keyb ^ ((drow & 7) << 4)));
                    oacc[dt] = __builtin_amdgcn_mfma_f32_32x32x16_bf16(af.v, vf, oacc[dt], 0, 0, 0);
                }
            }
        }
        __syncthreads();
    }

    // --- epilogue: combine hi halves of row-sums, normalize, store fp32 ---
    psum += __shfl_xor(psum, 32);  // lane L now has full sum for q = L&31
    float* obase = op + ((size_t)b * SLQ + (size_t)(q0 + 32 * wv)) * DD + l31;
    #pragma unroll
    for (int r = 0; r < 16; ++r) {
        const int qrow = (r & 3) + 8 * (r >> 2) + 4 * hi2;
        const float s  = __shfl(psum, qrow);
        const float rs = 1.0f / s;
        #pragma unroll
        for (int dt = 0; dt < 4; ++dt) {
            obase[(size_t)qrow * DD + 32 * dt] = oacc[dt][r] * rs;
        }
    }
}

extern "C" void kernel_launch(void* const* d_in, const int* in_sizes, int n_in,
                              void* d_out, int out_size, void* d_ws, size_t ws_size,
                              hipStream_t stream)
{
    const float* q = (const float*)d_in[0];
    const float* k = (const float*)d_in[1];
    const float* v = (const float*)d_in[2];
    const void*  m = d_in[3];  // bool mask; dtype (u8/i32/i64) auto-detected in-kernel
    float*       o = (float*)d_out;
    hipLaunchKernelGGL(attn_fwd, dim3((NB * SLQ) / QTILE), dim3(256), 0, stream,
                       q, k, v, m, o);
}

// Round 3
// 214.389 us; speedup vs baseline: 1.7016x; 1.7016x over previous
//
#include <hip/hip_runtime.h>
#include <stdint.h>

// Problem constants (B, LQ, LK, D fixed by the reference)
#define NB    32
#define SLQ   2048
#define SLK   2048
#define DD    128
#define QTILE 128          // q rows per workgroup (4 waves x 32)
#define KVB   64           // keys per block iteration
#define NKB   (SLK / KVB)  // 32

typedef __attribute__((ext_vector_type(8)))  short    bf16x8;
typedef __attribute__((ext_vector_type(16))) float    f32x16;
typedef __attribute__((ext_vector_type(4)))  float    f32x4v;
typedef __attribute__((ext_vector_type(4)))  uint32_t u32x4;
typedef __attribute__((ext_vector_type(2)))  uint32_t u32x2;

union FragU { uint32_t u[4]; bf16x8 v; };

// HW packed f32->bf16 (RNE), 1 inst per pair (T12 recipe, m214v22)
__device__ __forceinline__ uint32_t cvtpk(float lo, float hi) {
    uint32_t r;
    asm("v_cvt_pk_bf16_f32 %0, %1, %2" : "=v"(r) : "v"(lo), "v"(hi));
    return r;
}

__global__ __launch_bounds__(256, 2)
void attn_fwd(const float* __restrict__ qp, const float* __restrict__ kp,
              const float* __restrict__ vp, const void* __restrict__ mp,
              float* __restrict__ op)
{
    __shared__ short   k_lds[KVB * DD];     // [64 key][128 d] bf16, rows 256B, XOR-swizzled
    __shared__ short   vt_lds[DD * KVB];    // [128 d][64 key] bf16, rows 128B, XOR-swizzled
    __shared__ uint8_t m_lds[QTILE * 80];   // [128 q][64 k + pad]
    __shared__ int     det_flags;

    const int tid  = threadIdx.x;
    const int lane = tid & 63;
    const int wv   = tid >> 6;   // wave 0..3
    const int l31  = lane & 31;
    const int hi2  = lane >> 5;  // 0/1

    // XCD-chunked swizzle: 512 WGs, 8 XCDs -> each XCD gets 64 consecutive work ids
    const int bid = blockIdx.x;
    const int wg  = (bid & 7) * 64 + (bid >> 3);
    const int b   = wg >> 4;            // batch
    const int q0  = (wg & 15) * QTILE;  // q tile origin

    // ---- mask dtype self-detection (R2: FETCH proves u8; keep as safety) ----
    if (tid == 0) det_flags = 0;
    __syncthreads();
    {
        const u32x4 w = *(const u32x4*)((const char*)mp + tid * 16);
        const uint32_t any_hi    = (w.x | w.y | w.z | w.w) & 0xFFFFFF00u;
        const uint32_t any_mod84 = (w.y | w.w) & 0xFFu;
        const int f = (any_hi ? 1 : 0) | (any_mod84 ? 2 : 0);
        if (f) atomicOr(&det_flags, f);
    }
    __syncthreads();
    const int mflags = det_flags;
    const int mmode  = (mflags & 1) ? 0 : ((mflags & 2) ? 1 : 2);  // 0=u8, 1=i32, 2=i64

    // scale = log2(e)/sqrt(128): QK^T lands in log2 units -> softmax is bare exp2
    const float qsc = 0.12751744846458246f;

    // ---- persistent Q fragments (B-operand of swapped QK^T) ----
    bf16x8 qf[8];
    {
        const float* qrow = qp + ((size_t)b * SLQ + (size_t)(q0 + wv * 32 + l31)) * DD;
        #pragma unroll
        for (int ks = 0; ks < 8; ++ks) {
            f32x4v x0 = *(const f32x4v*)(qrow + 16 * ks + 8 * hi2);
            f32x4v x1 = *(const f32x4v*)(qrow + 16 * ks + 8 * hi2 + 4);
            FragU f;
            f.u[0] = cvtpk(x0.x * qsc, x0.y * qsc);
            f.u[1] = cvtpk(x0.z * qsc, x0.w * qsc);
            f.u[2] = cvtpk(x1.x * qsc, x1.y * qsc);
            f.u[3] = cvtpk(x1.z * qsc, x1.w * qsc);
            qf[ks] = f.v;
        }
    }

    f32x16 oacc[4];
    #pragma unroll
    for (int i = 0; i < 4; ++i)
        #pragma unroll
        for (int j = 0; j < 16; ++j) oacc[i][j] = 0.0f;
    float psum = 0.0f;

    const float* kb0 = kp + (size_t)b * SLK * DD;
    const float* vb0 = vp + (size_t)b * SLK * DD;
    const size_t mrow0 = ((size_t)b * SLQ + q0) * SLK;

    // ---- prefetch registers (T14: issue-early / write-late) ----
    f32x4v kreg[8];
    float  vreg[32];
    u32x4  mreg[2];

    const int vd  = tid & 127;
    const int vkh = tid >> 7;
    const int mqq = tid >> 1;
    const int mko = (tid & 1) * 32;

    #define LOAD_TILE(KB)                                                         \
        do {                                                                      \
            const int k0_ = (KB) * KVB;                                           \
            const float* kbase_ = kb0 + (size_t)k0_ * DD;                         \
            _Pragma("unroll")                                                     \
            for (int j = 0; j < 8; ++j)                                           \
                kreg[j] = *(const f32x4v*)(kbase_ + (j * 256 + tid) * 4);         \
            const float* vcol_ = vb0 + ((size_t)k0_ + 32 * vkh) * DD + vd;        \
            _Pragma("unroll")                                                     \
            for (int jj = 0; jj < 32; ++jj) vreg[jj] = vcol_[(size_t)jj * DD];    \
            if (mmode == 0) {                                                     \
                const uint8_t* ms_ = (const uint8_t*)mp + mrow0 +                 \
                                     (size_t)mqq * SLK + k0_ + mko;               \
                mreg[0] = *(const u32x4*)(ms_);                                   \
                mreg[1] = *(const u32x4*)(ms_ + 16);                              \
            }                                                                     \
        } while (0)

    LOAD_TILE(0);

    for (int kb = 0; kb < NKB; ++kb) {
        // ---- write LDS from prefetch regs (vmcnt waits land here, after a
        //      full compute phase has hidden the load latency) ----
        #pragma unroll
        for (int j = 0; j < 8; ++j) {
            const int flat = (j * 256 + tid) * 4;
            const int kk   = flat >> 7;
            const int dd2  = (flat & 127) * 2;
            u32x2 w2;
            w2.x = cvtpk(kreg[j].x, kreg[j].y);
            w2.y = cvtpk(kreg[j].z, kreg[j].w);
            *(u32x2*)((char*)k_lds + kk * 256 + (dd2 ^ ((kk & 7) << 4))) = w2;
        }
        {
            char* vrow = (char*)vt_lds + vd * 128;
            const int sw = (vd & 7) << 4;
            #pragma unroll
            for (int blk = 0; blk < 4; ++blk) {
                u32x4 w;
                w.x = cvtpk(vreg[8 * blk + 0], vreg[8 * blk + 1]);
                w.y = cvtpk(vreg[8 * blk + 2], vreg[8 * blk + 3]);
                w.z = cvtpk(vreg[8 * blk + 4], vreg[8 * blk + 5]);
                w.w = cvtpk(vreg[8 * blk + 6], vreg[8 * blk + 7]);
                *(u32x4*)(vrow + ((vkh * 64 + blk * 16) ^ sw)) = w;
            }
        }
        if (mmode == 0) {
            *(u32x4*)(&m_lds[mqq * 80 + mko])      = mreg[0];
            *(u32x4*)(&m_lds[mqq * 80 + mko + 16]) = mreg[1];
        } else if (mmode == 1) {
            const uint32_t* src = (const uint32_t*)mp + mrow0 + (size_t)mqq * SLK + kb * KVB + mko;
            #pragma unroll
            for (int j = 0; j < 32; ++j) m_lds[mqq * 80 + mko + j] = src[j] ? 1u : 0u;
        } else {
            const uint64_t* src = (const uint64_t*)mp + mrow0 + (size_t)mqq * SLK + kb * KVB + mko;
            #pragma unroll
            for (int j = 0; j < 32; ++j) m_lds[mqq * 80 + mko + j] = src[j] ? 1u : 0u;
        }
        __syncthreads();

        // ---- issue next tile's global loads (fly during compute) ----
        if (kb + 1 < NKB) LOAD_TILE(kb + 1);

        // ---- swapped QK^T: sacc[t] = S^T (keys 32t.. x 32 q), log2 units ----
        f32x16 sacc[2];
        #pragma unroll
        for (int t = 0; t < 2; ++t)
            #pragma unroll
            for (int j = 0; j < 16; ++j) sacc[t][j] = 0.0f;
        __builtin_amdgcn_s_setprio(1);
        #pragma unroll
        for (int t = 0; t < 2; ++t) {
            const int row = 32 * t + l31;
            const char* krow = (char*)k_lds + row * 256;
            const int sw = (row & 7) << 4;
            #pragma unroll
            for (int ks = 0; ks < 8; ++ks) {
                bf16x8 af = *(const bf16x8*)(krow + ((32 * ks + 16 * hi2) ^ sw));
                sacc[t] = __builtin_amdgcn_mfma_f32_32x32x16_bf16(af, qf[ks], sacc[t], 0, 0, 0);
            }
        }
        __builtin_amdgcn_s_setprio(0);

        // ---- softmax: p = exp2(s'), mask, f32 row-sum, pack bf16 pairs ----
        const uint8_t* mrow = &m_lds[(32 * wv + l31) * 80];
        uint32_t pw[2][8];
        #pragma unroll
        for (int t = 0; t < 2; ++t) {
            #pragma unroll
            for (int rr = 0; rr < 4; ++rr) {
                const uint32_t mw = *(const uint32_t*)(mrow + 32 * t + 8 * rr + 4 * hi2);
                float em[4];
                #pragma unroll
                for (int c = 0; c < 4; ++c) {
                    const float e = exp2f(sacc[t][4 * rr + c]);
                    em[c] = ((mw >> (8 * c)) & 0xffu) ? 0.0f : e;
                    psum += em[c];
                }
                pw[t][2 * rr]     = cvtpk(em[0], em[1]);
                pw[t][2 * rr + 1] = cvtpk(em[2], em[3]);
            }
        }

        // ---- PV: O[32q x 128d] += P[32x64] * V[64x128] ----
        #pragma unroll
        for (int t = 0; t < 2; ++t) {
            #pragma unroll
            for (int kss = 0; kss < 2; ++kss) {
                const uint32_t m0 = pw[t][4 * kss + 0];
                const uint32_t m1 = pw[t][4 * kss + 1];
                const uint32_t m2 = pw[t][4 * kss + 2];
                const uint32_t m3 = pw[t][4 * kss + 3];
                const uint32_t o0 = (uint32_t)__shfl_xor((int)m0, 32);
                const uint32_t o1 = (uint32_t)__shfl_xor((int)m1, 32);
                const uint32_t o2 = (uint32_t)__shfl_xor((int)m2, 32);
                const uint32_t o3 = (uint32_t)__shfl_xor((int)m3, 32);
                FragU af;
                af.u[0] = hi2 ? o2 : m0;
                af.u[1] = hi2 ? o3 : m1;
                af.u[2] = hi2 ? m2 : o0;
                af.u[3] = hi2 ? m3 : o1;
                const int keyb = 64 * t + 32 * kss + 16 * hi2;
                __builtin_amdgcn_s_setprio(1);
                #pragma unroll
                for (int dt = 0; dt < 4; ++dt) {
                    const int drow = 32 * dt + l31;
                    bf16x8 vf = *(const bf16x8*)((char*)vt_lds + drow * 128 +
                                                 (keyb ^ ((drow & 7) << 4)));
                    oacc[dt] = __builtin_amdgcn_mfma_f32_32x32x16_bf16(af.v, vf, oacc[dt], 0, 0, 0);
                }
                __builtin_amdgcn_s_setprio(0);
            }
        }
        __syncthreads();
    }

    // ---- epilogue: combine halves of row-sums, normalize, store fp32 ----
    psum += __shfl_xor(psum, 32);
    float* obase = op + ((size_t)b * SLQ + (size_t)(q0 + 32 * wv)) * DD + l31;
    #pragma unroll
    for (int r = 0; r < 16; ++r) {
        const int qrow = (r & 3) + 8 * (r >> 2) + 4 * hi2;
        const float s  = __shfl(psum, qrow);
        const float rs = 1.0f / s;
        #pragma unroll
        for (int dt = 0; dt < 4; ++dt) {
            obase[(size_t)qrow * DD + 32 * dt] = oacc[dt][r] * rs;
        }
    }
}

extern "C" void kernel_launch(void* const* d_in, const int* in_sizes, int n_in,
                              void* d_out, int out_size, void* d_ws, size_t ws_size,
                              hipStream_t stream)
{
    const float* q = (const float*)d_in[0];
    const float* k = (const float*)d_in[1];
    const float* v = (const float*)d_in[2];
    const void*  m = d_in[3];
    float*       o = (float*)d_out;
    hipLaunchKernelGGL(attn_fwd, dim3((NB * SLQ) / QTILE), dim3(256), 0, stream,
                       q, k, v, m, o);
}